// Round 9
// baseline (1433.920 us; speedup 1.0000x reference)
//
#include <hip/hip_runtime.h>

typedef unsigned short u16;
typedef unsigned int   u32;
typedef __attribute__((ext_vector_type(8))) short short8;
typedef __attribute__((ext_vector_type(4))) float f32x4;

struct __align__(8) u16x4 { u16 x, y, z, w; };

#define NL 7
#define M_DIM 131072              // B*S = 256*512

#define VMW(N) asm volatile("s_waitcnt vmcnt(" #N ")" ::: "memory")
#define LGW()  asm volatile("s_waitcnt lgkmcnt(0)" ::: "memory")
#define BAR()  __builtin_amdgcn_s_barrier()
#define SB0()  __builtin_amdgcn_sched_barrier(0)
#define PRIO1  __builtin_amdgcn_s_setprio(1)
#define PRIO0  __builtin_amdgcn_s_setprio(0)
#define MFMA   __builtin_amdgcn_mfma_f32_16x16x32_bf16

__device__ __forceinline__ float b2f(u16 u) {
  union { float f; u32 i; } c; c.i = ((u32)u) << 16; return c.f;
}
__device__ __forceinline__ u16 f2b(float f) {
  union { float f; u32 i; } c; c.f = f;
  u32 r = c.i + 0x7FFFu + ((c.i >> 16) & 1u);
  return (u16)(r >> 16);
}
__device__ __forceinline__ void gload16(const void* g, void* l) {
  __builtin_amdgcn_global_load_lds((const __attribute__((address_space(1))) void*)g,
                                   (__attribute__((address_space(3))) void*)l, 16, 0, 0);
}
// XOR-swizzled [R][256] tile index: chunk = col>>3 (8-u16 / 16B units)
__device__ __forceinline__ int xIdx(int row, int chunk) {
  return row * 256 + (((chunk) ^ (row & 7)) << 3);
}

// ---------------- weight conversion (fp32 -> bf16, transposed to [N][K]) ----------------

__global__ __launch_bounds__(256) void conv_w1_k(const float* __restrict__ w1, u16* __restrict__ wT) {
  int idx = blockIdx.x * 256 + threadIdx.x;            // NL*256*256 ; [i][n][k]
  int i = idx >> 16, rem = idx & 65535;
  int n = rem >> 8, k = rem & 255;
  wT[idx] = f2b(w1[(i << 16) + (k << 8) + n]);
}

__global__ __launch_bounds__(256) void conv_wd_k(const float* __restrict__ wd, u16* __restrict__ wT) {
  int idx = blockIdx.x * 256 + threadIdx.x;            // NL*256*512 ; [i][n][k2], k2=tap*256+k
  int i = idx / 131072, rem = idx & 131071;
  int n = rem >> 9, k2 = rem & 511;
  int tap = k2 >> 8, k = k2 & 255;
  wT[idx] = f2b(wd[(((i * 2 + tap) << 8) + k) * 256 + n]);
}

__global__ __launch_bounds__(256) void conv_weg_k(const float* __restrict__ we, const float* __restrict__ wg,
                                                  u16* __restrict__ wT) {
  int idx = blockIdx.x * 256 + threadIdx.x;            // NL*2*256*256 ; [i][src][n][k]
  int i = idx / 131072, rem = idx & 131071;
  int src = rem >> 16, n = (rem >> 8) & 255, k = rem & 255;
  const float* W = src ? wg : we;
  wT[idx] = f2b(W[((i << 8) + k) * 256 + n]);
}

__global__ __launch_bounds__(256) void conv_wo_k(const float* __restrict__ outW, u16* __restrict__ wTo) {
  int idx = blockIdx.x * 256 + threadIdx.x;            // 32*256 ; [v][k]
  int v = idx >> 8, k = idx & 255;
  wTo[idx] = f2b(outW[k * 32 + v]);
}

// ---------------- zlat = z @ latent_W + latent_b  [256,256] fp32 ----------------

__global__ __launch_bounds__(256) void zlat_k(const float* __restrict__ z, const float* __restrict__ W,
                                              const float* __restrict__ bias, float* __restrict__ zlat) {
  int b = blockIdx.x, c = threadIdx.x;
  float acc = bias[c];
  for (int l = 0; l < 256; ++l) acc += z[b * 256 + l] * W[l * 256 + c];
  zlat[b * 256 + c] = acc;
}

// ---------------- embed: h = bf16(emb[x] + zlat) ----------------

__global__ __launch_bounds__(256) void embed_k(const int* __restrict__ x, const float* __restrict__ emb,
                                               const float* __restrict__ zlat, u16* __restrict__ h) {
  int wave = threadIdx.x >> 6, lane = threadIdx.x & 63;
  int r = blockIdx.x * 4 + wave;
  int c = lane * 4;
  int tok = x[r];
  int bi = r >> 9;
  float4 ev = *(const float4*)&emb[tok * 256 + c];
  float4 zv = *(const float4*)&zlat[bi * 256 + c];
  u16x4 hb;
  hb.x = f2b(ev.x + zv.x); hb.y = f2b(ev.y + zv.y);
  hb.z = f2b(ev.z + zv.z); hb.w = f2b(ev.w + zv.w);
  *(u16x4*)&h[(long)r * 256 + c] = hb;
}

// ---------------- gemm1: V = lrelu(LN2( lrelu(LN1(h)) @ w1 + b1 )) ----------------
// r4 proven shape: 48KB LDS -> 3 blocks/CU.

__global__ __launch_bounds__(256, 3) void gemm1_k(
    const u16* __restrict__ h, const u16* __restrict__ WT,
    const float* __restrict__ ln1g, const float* __restrict__ ln1b,
    const float* __restrict__ bias,
    const float* __restrict__ ln2g, const float* __restrict__ ln2b,
    u16* __restrict__ V)
{
  __shared__ __align__(16) u16 lA[64 * 256];     // 32768 B, LN1(h) tile, XOR-swizzled
  __shared__ __align__(16) u16 lB[256 * 32];     // 16384 B, per-kt B staging
  float* pS  = (float*)lB;
  float* pQ  = (float*)(lB + 512);
  float* muA = (float*)(lB + 1024);
  float* rsA = (float*)(lB + 1152);
  const int tid = threadIdx.x;
  const int lane = tid & 63;
  const int wv = tid >> 6;            // 0..3
  const int wc = wv * 64;
  const int m0 = blockIdx.x * 64;
  const int rA = tid >> 2;            // 0..63
  const int cSw = ((((tid & 3) - ((tid >> 3) & 3)) & 3)) * 8;
  const int lr = lane & 15;
  const int quad = lane >> 4;
  const int sw = ((quad + ((lr >> 1) & 3)) & 3) * 8;

  // ---- prologue: LN1 + lrelu of 16 rows per wave -> lA ----
  {
    const int half = lane >> 5, l5 = lane & 31;
    float4 ga = *(const float4*)&ln1g[l5 * 8];
    float4 gb = *(const float4*)&ln1g[l5 * 8 + 4];
    float4 ba = *(const float4*)&ln1b[l5 * 8];
    float4 bb = *(const float4*)&ln1b[l5 * 8 + 4];
    #pragma unroll 4
    for (int it = 0; it < 8; ++it) {
      int row = wv * 16 + it * 2 + half;
      uint4 hv = *(const uint4*)(h + (long)(m0 + row) * 256 + l5 * 8);
      float v0 = b2f((u16)(hv.x & 0xffff)), v1 = b2f((u16)(hv.x >> 16));
      float v2 = b2f((u16)(hv.y & 0xffff)), v3 = b2f((u16)(hv.y >> 16));
      float v4 = b2f((u16)(hv.z & 0xffff)), v5 = b2f((u16)(hv.z >> 16));
      float v6 = b2f((u16)(hv.w & 0xffff)), v7 = b2f((u16)(hv.w >> 16));
      float s = v0 + v1 + v2 + v3 + v4 + v5 + v6 + v7;
      float q = v0*v0 + v1*v1 + v2*v2 + v3*v3 + v4*v4 + v5*v5 + v6*v6 + v7*v7;
      #pragma unroll
      for (int o = 1; o < 32; o <<= 1) { s += __shfl_xor(s, o); q += __shfl_xor(q, o); }
      float mu = s * 0.00390625f;
      float var = q * 0.00390625f - mu * mu;
      float rs = rsqrtf(var + 1e-5f);
      float y0 = (v0 - mu) * rs * ga.x + ba.x; y0 = y0 >= 0.f ? y0 : 0.01f * y0;
      float y1 = (v1 - mu) * rs * ga.y + ba.y; y1 = y1 >= 0.f ? y1 : 0.01f * y1;
      float y2 = (v2 - mu) * rs * ga.z + ba.z; y2 = y2 >= 0.f ? y2 : 0.01f * y2;
      float y3 = (v3 - mu) * rs * ga.w + ba.w; y3 = y3 >= 0.f ? y3 : 0.01f * y3;
      float y4 = (v4 - mu) * rs * gb.x + bb.x; y4 = y4 >= 0.f ? y4 : 0.01f * y4;
      float y5 = (v5 - mu) * rs * gb.y + bb.y; y5 = y5 >= 0.f ? y5 : 0.01f * y5;
      float y6 = (v6 - mu) * rs * gb.z + bb.z; y6 = y6 >= 0.f ? y6 : 0.01f * y6;
      float y7 = (v7 - mu) * rs * gb.w + bb.w; y7 = y7 >= 0.f ? y7 : 0.01f * y7;
      uint4 ov;
      ov.x = (u32)f2b(y0) | ((u32)f2b(y1) << 16);
      ov.y = (u32)f2b(y2) | ((u32)f2b(y3) << 16);
      ov.z = (u32)f2b(y4) | ((u32)f2b(y5) << 16);
      ov.w = (u32)f2b(y6) | ((u32)f2b(y7) << 16);
      *(uint4*)&lA[xIdx(row, l5)] = ov;
    }
  }

  f32x4 acc[4][4];
  #pragma unroll
  for (int i = 0; i < 4; ++i)
    #pragma unroll
    for (int j = 0; j < 4; ++j) {
      acc[i][j][0] = 0.f; acc[i][j][1] = 0.f; acc[i][j][2] = 0.f; acc[i][j][3] = 0.f;
    }

  for (int kt = 0; kt < 8; ++kt) {
    const long bofs = (long)rA * 256 + kt * 32 + cSw;
    #pragma unroll
    for (int j = 0; j < 4; ++j)
      gload16(WT + bofs + (long)(64 * j) * 256, &lB[tid * 8 + j * 2048]);
    __syncthreads();

    short8 af[4], bfr[4];
    #pragma unroll
    for (int mt = 0; mt < 4; ++mt)
      af[mt] = *(const short8*)&lA[xIdx(mt * 16 + lr, 4 * kt + quad)];
    #pragma unroll
    for (int nt = 0; nt < 4; ++nt)
      bfr[nt] = *(const short8*)&lB[(wc + nt * 16 + lr) * 32 + sw];
    #pragma unroll
    for (int mt = 0; mt < 4; ++mt)
      #pragma unroll
      for (int nt = 0; nt < 4; ++nt)
        acc[mt][nt] = MFMA(af[mt], bfr[nt], acc[mt][nt], 0, 0, 0);
    __syncthreads();
  }

  // ---- epilogue: bias + LN2 + lrelu -> V ----
  float biasv[4], gv[4], bv[4];
  #pragma unroll
  for (int nt = 0; nt < 4; ++nt) {
    int n = wc + nt * 16 + lr;
    biasv[nt] = bias[n]; gv[nt] = ln2g[n]; bv[nt] = ln2b[n];
  }
  #pragma unroll
  for (int mt = 0; mt < 4; ++mt)
    #pragma unroll
    for (int r = 0; r < 4; ++r) {
      float s = 0.f, q = 0.f;
      #pragma unroll
      for (int nt = 0; nt < 4; ++nt) {
        float v = acc[mt][nt][r] + biasv[nt];
        acc[mt][nt][r] = v;
        s += v; q += v * v;
      }
      #pragma unroll
      for (int o = 1; o < 16; o <<= 1) { s += __shfl_xor(s, o); q += __shfl_xor(q, o); }
      if (lr == 0) { pS[(mt * 16 + quad * 4 + r) * 4 + wv] = s; pQ[(mt * 16 + quad * 4 + r) * 4 + wv] = q; }
    }
  __syncthreads();
  if (tid < 64) {
    float S = pS[tid * 4 + 0] + pS[tid * 4 + 1] + pS[tid * 4 + 2] + pS[tid * 4 + 3];
    float Q = pQ[tid * 4 + 0] + pQ[tid * 4 + 1] + pQ[tid * 4 + 2] + pQ[tid * 4 + 3];
    float mu = S * 0.00390625f;
    float var = Q * 0.00390625f - mu * mu;
    muA[tid] = mu; rsA[tid] = rsqrtf(var + 1e-5f);
  }
  __syncthreads();
  #pragma unroll
  for (int mt = 0; mt < 4; ++mt)
    #pragma unroll
    for (int r = 0; r < 4; ++r) {
      int row = mt * 16 + quad * 4 + r;
      float mu = muA[row], rs = rsA[row];
      #pragma unroll
      for (int nt = 0; nt < 4; ++nt) {
        float y = (acc[mt][nt][r] - mu) * rs * gv[nt] + bv[nt];
        y = y >= 0.f ? y : 0.01f * y;
        V[(long)(m0 + row) * 256 + wc + nt * 16 + lr] = f2b(y);
      }
    }
}

// ---------------- FUSED conv+LN3+lrelu -> P(LDS) -> gate GEMMs -> h update ----------------
// r9: TRUE 8-phase schedule (T3+T4+T5). 32 tiles of BK=32 (16 conv + 8 E + 8 G)
// in ONE 3-buffer rotation (3x24KB). Per tile, 2 phases:
//   {ds_read subtile -> BAR -> issue 1-2 gloads(tile t+2) -> lgkmcnt(0) ->
//    sched_barrier -> setprio(1) -> 8 MFMA -> setprio(0) -> BAR}
// vmcnt counted ONCE per tile (3 or 2 = loads of tile t+2 in flight), never 0
// until the tail. Loads get ~2 tiles of flight. Epilogue-1 uses lgkm-only
// barriers so phase-2 prefetch stays in flight. LDS 144KB -> 1 block/CU.

__global__ __launch_bounds__(512, 2) void conv_gate_k(
    const u16* __restrict__ A,      // v  [M][256] bf16
    const u16* __restrict__ WTd,    // [256][512]  (n-major; k2 = tap*256+k)
    int dil,
    const float* __restrict__ bd3, const float* __restrict__ g3, const float* __restrict__ bb3,
    const u16* __restrict__ WTe, const u16* __restrict__ WTg,   // [256][256] each
    const float* __restrict__ bev_, const float* __restrict__ bgv_,
    u16* __restrict__ h)
{
  __shared__ __align__(16) u16 pT[128 * 256];    // 65536 B : P tile, XOR-swizzled
  __shared__ __align__(16) u16 stg[3][12288];    // 3 x 24576 B : A [0,4096), W [4096,12288)
  __shared__ float pS[128][4], pQ[128][4];       // 4096 B
  __shared__ float muA[128], rsA[128];           // 1024 B

  const int tid = threadIdx.x;
  const int lane = tid & 63;
  const int wv = tid >> 6;            // 0..7
  const int mw = wv >> 2;             // 0..1
  const int nw = wv & 3;              // 0..3
  const int rb = mw * 64;
  const int wc = nw * 64;
  const int m0 = blockIdx.x * 128;
  const int rA = tid >> 2;            // 0..127
  const int cSw = ((((tid & 3) - ((tid >> 3) & 3)) & 3)) * 8;
  const int lr = lane & 15;
  const int quad = lane >> 4;
  const int sw = ((quad + ((lr >> 1) & 3)) & 3) * 8;
  const int mm = m0 + rA;
  const int s1 = mm & 511;
  const short8 zero8 = {0, 0, 0, 0, 0, 0, 0, 0};

  // tap0 zero predicate per frag row
  bool zz[4];
  #pragma unroll
  for (int mt = 0; mt < 4; ++mt)
    zz[mt] = ((m0 + rb + mt * 16 + lr) & 511) < dil;

  // thread-baked base pointers
  const int rowA0 = (s1 >= dil) ? (mm - dil) : mm;
  const u16* pA0 = A + (long)rowA0 * 256 + cSw;    // tap0 rows (tiles 0-7, col kt*32)
  const u16* pA1 = A + (long)mm * 256 + cSw;       // tap1 rows (tiles 8-15)
  const u16* pWd = WTd + (long)rA * 512 + cSw;     // rows rA / rA+128 (+128*512)
  const u16* pWe = WTe + (long)rA * 256 + cSw;     // rows rA / rA+128 (+128*256)
  const u16* pWg = WTg + (long)rA * 256 + cSw;

  // staging helpers (all targets lane-linear: wave-uniform base + tid*16B)
  auto stA   = [&](int kt, int nb) {               // conv A slice kt (1 load, 8KB)
    const u16* pa = (kt < 8 ? pA0 : pA1) + (kt & 7) * 32;
    gload16(pa, &stg[nb][tid * 8]);
  };
  auto stW1a = [&](int kt, int nb) { gload16(pWd + kt * 32,             &stg[nb][4096 + tid * 8]); };
  auto stW1b = [&](int kt, int nb) { gload16(pWd + 128 * 512 + kt * 32, &stg[nb][8192 + tid * 8]); };
  auto stW2a = [&](const u16* pw, int j, int nb) { gload16(pw + j * 32,             &stg[nb][4096 + tid * 8]); };
  auto stW2b = [&](const u16* pw, int j, int nb) { gload16(pw + 128 * 256 + j * 32, &stg[nb][8192 + tid * 8]); };
  // frag readers
  auto rdA = [&](int bb, int mt) -> short8 { return *(const short8*)&stg[bb][(rb + mt * 16 + lr) * 32 + sw]; };
  auto rdB = [&](int bb, int nt) -> short8 { return *(const short8*)&stg[bb][4096 + (wc + nt * 16 + lr) * 32 + sw]; };
  auto rdP = [&](int j, int mt) -> short8 { return *(const short8*)&pT[xIdx(rb + mt * 16 + lr, 4 * j + quad)]; };

  f32x4 acc[4][4];
  #pragma unroll
  for (int i = 0; i < 4; ++i)
    #pragma unroll
    for (int j = 0; j < 4; ++j) {
      acc[i][j][0] = 0.f; acc[i][j][1] = 0.f; acc[i][j][2] = 0.f; acc[i][j][3] = 0.f;
    }

  // phase-1 tile body (t = 0..15; stage targets tile t+2)
  auto p1_tile = [&](int t) {
    const int bb = t % 3, nb = (t + 2) % 3;
    const bool tap0 = t < 8;
    // ---- phase A ----
    short8 af0 = rdA(bb, 0), af1 = rdA(bb, 1);
    short8 b0 = rdB(bb, 0), b1 = rdB(bb, 1), b2 = rdB(bb, 2), b3 = rdB(bb, 3);
    if (tap0) { if (zz[0]) af0 = zero8; if (zz[1]) af1 = zero8; }
    BAR();                                   // all waves past tile t-1 -> nb safe to write
    if (t <= 13) { stA(t + 2, nb); stW1a(t + 2, nb); }
    else         { stW2a(pWe, t - 14, nb); } // t=14,15 -> prefetch We slices 0,1
    LGW(); SB0();
    PRIO1;
    acc[0][0] = MFMA(af0, b0, acc[0][0], 0, 0, 0);
    acc[0][1] = MFMA(af0, b1, acc[0][1], 0, 0, 0);
    acc[0][2] = MFMA(af0, b2, acc[0][2], 0, 0, 0);
    acc[0][3] = MFMA(af0, b3, acc[0][3], 0, 0, 0);
    acc[1][0] = MFMA(af1, b0, acc[1][0], 0, 0, 0);
    acc[1][1] = MFMA(af1, b1, acc[1][1], 0, 0, 0);
    acc[1][2] = MFMA(af1, b2, acc[1][2], 0, 0, 0);
    acc[1][3] = MFMA(af1, b3, acc[1][3], 0, 0, 0);
    PRIO0;
    BAR();
    // ---- phase B ----
    short8 af2 = rdA(bb, 2), af3 = rdA(bb, 3);
    if (tap0) { if (zz[2]) af2 = zero8; if (zz[3]) af3 = zero8; }
    BAR();
    if (t <= 13) { stW1b(t + 2, nb); }
    else         { stW2b(pWe, t - 14, nb); }
    LGW(); SB0();
    PRIO1;
    acc[2][0] = MFMA(af2, b0, acc[2][0], 0, 0, 0);
    acc[2][1] = MFMA(af2, b1, acc[2][1], 0, 0, 0);
    acc[2][2] = MFMA(af2, b2, acc[2][2], 0, 0, 0);
    acc[2][3] = MFMA(af2, b3, acc[2][3], 0, 0, 0);
    acc[3][0] = MFMA(af3, b0, acc[3][0], 0, 0, 0);
    acc[3][1] = MFMA(af3, b1, acc[3][1], 0, 0, 0);
    acc[3][2] = MFMA(af3, b2, acc[3][2], 0, 0, 0);
    acc[3][3] = MFMA(af3, b3, acc[3][3], 0, 0, 0);
    PRIO0;
  };

  // ---- prologue: stage tiles 0,1; tile 1's loads stay in flight ----
  stA(0, 0); stW1a(0, 0); stW1b(0, 0);
  stA(1, 1); stW1a(1, 1); stW1b(1, 1);
  VMW(3);
  BAR();

  #pragma unroll
  for (int t = 0; t <= 13; ++t) { p1_tile(t); VMW(3); BAR(); }
  p1_tile(14); VMW(2); BAR();
  p1_tile(15); VMW(2); BAR();

  // ---- epilogue 1: bias + LN3 stats + lrelu -> pT (lgkm-only barriers!) ----
  {
    float b3v[4], g3v[4], o3v[4];
    #pragma unroll
    for (int nt = 0; nt < 4; ++nt) {
      int n = wc + nt * 16 + lr;
      b3v[nt] = bd3[n]; g3v[nt] = g3[n]; o3v[nt] = bb3[n];
    }
    #pragma unroll
    for (int mt = 0; mt < 4; ++mt)
      #pragma unroll
      for (int r = 0; r < 4; ++r) {
        float s = 0.f, q = 0.f;
        #pragma unroll
        for (int nt = 0; nt < 4; ++nt) {
          float v = acc[mt][nt][r] + b3v[nt];
          acc[mt][nt][r] = v;
          s += v; q += v * v;
        }
        #pragma unroll
        for (int o = 1; o < 16; o <<= 1) { s += __shfl_xor(s, o); q += __shfl_xor(q, o); }
        if (lr == 0) {
          int row = rb + mt * 16 + quad * 4 + r;
          pS[row][nw] = s; pQ[row][nw] = q;
        }
      }
    LGW(); BAR();
    if (tid < 128) {
      float S = pS[tid][0] + pS[tid][1] + pS[tid][2] + pS[tid][3];
      float Q = pQ[tid][0] + pQ[tid][1] + pQ[tid][2] + pQ[tid][3];
      float mu = S * 0.00390625f;
      float var = Q * 0.00390625f - mu * mu;
      muA[tid] = mu; rsA[tid] = rsqrtf(var + 1e-5f);
    }
    LGW(); BAR();
    #pragma unroll
    for (int mt = 0; mt < 4; ++mt)
      #pragma unroll
      for (int r = 0; r < 4; ++r) {
        int row = rb + mt * 16 + quad * 4 + r;
        float mu = muA[row], rs = rsA[row];
        #pragma unroll
        for (int nt = 0; nt < 4; ++nt) {
          int col = wc + nt * 16 + lr;
          float y = (acc[mt][nt][r] - mu) * rs * g3v[nt] + o3v[nt];
          y = y >= 0.f ? y : 0.01f * y;
          pT[xIdx(row, col >> 3) + (col & 7)] = f2b(y);
        }
      }
    LGW(); BAR();                      // pT visible; We0/We1 still in flight
  }

  // ---- phase 2: accE (tiles 16-23), accG (tiles 24-31) ----
  f32x4 accE[4][4], accG[4][4];
  #pragma unroll
  for (int i = 0; i < 4; ++i)
    #pragma unroll
    for (int j = 0; j < 4; ++j) {
      accE[i][j][0] = 0.f; accE[i][j][1] = 0.f; accE[i][j][2] = 0.f; accE[i][j][3] = 0.f;
      accG[i][j][0] = 0.f; accG[i][j][1] = 0.f; accG[i][j][2] = 0.f; accG[i][j][3] = 0.f;
    }

  auto p2_tile = [&](int t, int j, f32x4 (&ac)[4][4], const u16* stSrc, int stJ, int nloads) {
    const int bb = t % 3, nb = (t + 2) % 3;
    // ---- phase A ----
    short8 p0 = rdP(j, 0), p1 = rdP(j, 1);
    short8 w0 = rdB(bb, 0), w1 = rdB(bb, 1), w2 = rdB(bb, 2), w3 = rdB(bb, 3);
    BAR();
    if (nloads) stW2a(stSrc, stJ, nb);
    LGW(); SB0();
    PRIO1;
    ac[0][0] = MFMA(p0, w0, ac[0][0], 0, 0, 0);
    ac[0][1] = MFMA(p0, w1, ac[0][1], 0, 0, 0);
    ac[0][2] = MFMA(p0, w2, ac[0][2], 0, 0, 0);
    ac[0][3] = MFMA(p0, w3, ac[0][3], 0, 0, 0);
    ac[1][0] = MFMA(p1, w0, ac[1][0], 0, 0, 0);
    ac[1][1] = MFMA(p1, w1, ac[1][1], 0, 0, 0);
    ac[1][2] = MFMA(p1, w2, ac[1][2], 0, 0, 0);
    ac[1][3] = MFMA(p1, w3, ac[1][3], 0, 0, 0);
    PRIO0;
    BAR();
    // ---- phase B ----
    short8 p2 = rdP(j, 2), p3 = rdP(j, 3);
    BAR();
    if (nloads) stW2b(stSrc, stJ, nb);
    LGW(); SB0();
    PRIO1;
    ac[2][0] = MFMA(p2, w0, ac[2][0], 0, 0, 0);
    ac[2][1] = MFMA(p2, w1, ac[2][1], 0, 0, 0);
    ac[2][2] = MFMA(p2, w2, ac[2][2], 0, 0, 0);
    ac[2][3] = MFMA(p2, w3, ac[2][3], 0, 0, 0);
    ac[3][0] = MFMA(p3, w0, ac[3][0], 0, 0, 0);
    ac[3][1] = MFMA(p3, w1, ac[3][1], 0, 0, 0);
    ac[3][2] = MFMA(p3, w2, ac[3][2], 0, 0, 0);
    ac[3][3] = MFMA(p3, w3, ac[3][3], 0, 0, 0);
    PRIO0;
  };

  #pragma unroll
  for (int t = 16; t <= 21; ++t) { p2_tile(t, t - 16, accE, pWe, t - 14, 1); VMW(2); BAR(); }
  p2_tile(22, 6, accE, pWg, 0, 1); VMW(2); BAR();
  p2_tile(23, 7, accE, pWg, 1, 1); VMW(2); BAR();
  #pragma unroll
  for (int t = 24; t <= 29; ++t) { p2_tile(t, t - 24, accG, pWg, t - 22, 1); VMW(2); BAR(); }
  p2_tile(30, 6, accG, pWg, 0, 0); VMW(0); BAR();
  p2_tile(31, 7, accG, pWg, 0, 0);

  // ---- epilogue 2: h += (E+be) * sigmoid(G+bg) ----
  float bev[4], bgv[4];
  #pragma unroll
  for (int nt = 0; nt < 4; ++nt) {
    int n = wc + nt * 16 + lr;
    bev[nt] = bev_[n]; bgv[nt] = bgv_[n];
  }
  #pragma unroll
  for (int mt = 0; mt < 4; ++mt)
    #pragma unroll
    for (int r = 0; r < 4; ++r) {
      int row = rb + mt * 16 + quad * 4 + r;
      long off = (long)(m0 + row) * 256;
      #pragma unroll
      for (int nt = 0; nt < 4; ++nt) {
        int n = wc + nt * 16 + lr;
        float e = accE[mt][nt][r] + bev[nt];
        float gg = accG[mt][nt][r] + bgv[nt];
        float hn = e * (1.f / (1.f + expf(-gg))) + b2f(h[off + n]);
        h[off + n] = f2b(hn);
      }
    }
}

// ---------------- final: MFMA logits [M,32], log_softmax, gather next token ----------------

__global__ __launch_bounds__(256) void final_k(const u16* __restrict__ h, const u16* __restrict__ WTo,
                                               const float* __restrict__ outb, const int* __restrict__ x,
                                               float* __restrict__ out) {
  __shared__ u16 lW[32 * 264];
  const int tid = threadIdx.x;
  const int lane = tid & 63;
  const int wv = tid >> 6;
  const int mBase = blockIdx.x * 256 + wv * 64;

  #pragma unroll
  for (int j = 0; j < 4; ++j) {
    int chunk = tid + 256 * j;
    int v = chunk >> 5, k8 = chunk & 31;
    uint4 w4 = *(const uint4*)(WTo + v * 256 + k8 * 8);
    *(uint4*)&lW[v * 264 + k8 * 8] = w4;
  }
  __syncthreads();

  const int lq = (lane >> 4) * 8;
  const int lr = lane & 15;
  const int quad = lane >> 4;

  f32x4 acc[4][2];
  #pragma unroll
  for (int mt = 0; mt < 4; ++mt) {
    acc[mt][0][0] = 0.f; acc[mt][0][1] = 0.f; acc[mt][0][2] = 0.f; acc[mt][0][3] = 0.f;
    acc[mt][1][0] = 0.f; acc[mt][1][1] = 0.f; acc[mt][1][2] = 0.f; acc[mt][1][3] = 0.f;
  }

  for (int kt = 0; kt < 8; ++kt) {
    short8 bf0 = *(const short8*)&lW[lr * 264 + kt * 32 + lq];
    short8 bf1 = *(const short8*)&lW[(16 + lr) * 264 + kt * 32 + lq];
    #pragma unroll
    for (int mt = 0; mt < 4; ++mt) {
      short8 af = *(const short8*)(h + (long)(mBase + mt * 16 + lr) * 256 + kt * 32 + lq);
      acc[mt][0] = MFMA(af, bf0, acc[mt][0], 0, 0, 0);
      acc[mt][1] = MFMA(af, bf1, acc[mt][1], 0, 0, 0);
    }
  }

  float ob0 = outb[lr], ob1 = outb[16 + lr];
  #pragma unroll
  for (int mt = 0; mt < 4; ++mt)
    #pragma unroll
    for (int r = 0; r < 4; ++r) {
      int row = mBase + mt * 16 + quad * 4 + r;
      float lo = acc[mt][0][r] + ob0;
      float hi = acc[mt][1][r] + ob1;
      float mx = fmaxf(lo, hi);
      #pragma unroll
      for (int o = 1; o < 16; o <<= 1) mx = fmaxf(mx, __shfl_xor(mx, o));
      float se = expf(lo - mx) + expf(hi - mx);
      #pragma unroll
      for (int o = 1; o < 16; o <<= 1) se += __shfl_xor(se, o);
      int s = row & 511;
      int xa = (s == 511) ? row : (row + 1);
      int tok = x[xa];
      float lg = (tok < 16) ? lo : hi;
      float lp = lg - mx - logf(se);
      if (s != 511 && lr == (tok & 15))
        out[(row >> 9) * 511 + s] = lp;
    }
}

// ---------------- launch ----------------

extern "C" void kernel_launch(void* const* d_in, const int* in_sizes, int n_in,
                              void* d_out, int out_size, void* d_ws, size_t ws_size,
                              hipStream_t stream) {
  const int*   x    = (const int*)d_in[0];
  const float* z    = (const float*)d_in[1];
  const float* emb  = (const float*)d_in[2];
  const float* latW = (const float*)d_in[3];
  const float* latb = (const float*)d_in[4];
  const float* ln1g = (const float*)d_in[5];
  const float* ln1b = (const float*)d_in[6];
  const float* w1   = (const float*)d_in[7];
  const float* b1   = (const float*)d_in[8];
  const float* ln2g = (const float*)d_in[9];
  const float* ln2b = (const float*)d_in[10];
  const float* wd   = (const float*)d_in[11];
  const float* bd   = (const float*)d_in[12];
  const float* ln3g = (const float*)d_in[13];
  const float* ln3b = (const float*)d_in[14];
  const float* we   = (const float*)d_in[15];
  const float* be   = (const float*)d_in[16];
  const float* wg   = (const float*)d_in[17];
  const float* bg   = (const float*)d_in[18];
  const float* outW = (const float*)d_in[19];
  const float* outb = (const float*)d_in[20];

  char* ws = (char*)d_ws;
  u16*   h    = (u16*)(ws + 0);               //  67108864  bf16 residual
  u16*   bufA = (u16*)(ws + 67108864);        //  67108864  v
  float* zlat = (float*)(ws + 201326592);     //    262144
  u16*   wT1  = (u16*)(ws + 201588736);       //    917504  [i][n][k]
  u16*   wTd  = (u16*)(ws + 202506240);       //   1835008  [i][n][tap*256+k]
  u16*   wTeg = (u16*)(ws + 204341248);       //   1835008  [i][src][n][k]
  u16*   wTo  = (u16*)(ws + 206176256);       //     16384  [v][k]

  conv_w1_k <<<1792, 256, 0, stream>>>(w1, wT1);
  conv_wd_k <<<3584, 256, 0, stream>>>(wd, wTd);
  conv_weg_k<<<3584, 256, 0, stream>>>(we, wg, wTeg);
  conv_wo_k <<<32, 256, 0, stream>>>(outW, wTo);
  zlat_k    <<<256, 256, 0, stream>>>(z, latW, latb, zlat);
  embed_k   <<<M_DIM / 4, 256, 0, stream>>>(x, emb, zlat, h);

  for (int i = 0; i < NL; ++i) {
    int d = 1 << i;
    // v = lrelu(LN2( lrelu(LN1(h)) @ w1 + b1 ))   -> bufA
    gemm1_k<<<M_DIM / 64, 256, 0, stream>>>(
        h, wT1 + i * 65536, ln1g + i * 256, ln1b + i * 256, b1 + i * 256,
        ln2g + i * 256, ln2b + i * 256, bufA);
    // p = lrelu(LN3(conv)) kept in LDS; h += (p@we+be)*sigmoid(p@wg+bg)
    conv_gate_k<<<M_DIM / 128, 512, 0, stream>>>(
        bufA, wTd + i * 131072, d,
        bd + i * 256, ln3g + i * 256, ln3b + i * 256,
        wTeg + i * 131072, wTeg + i * 131072 + 65536,
        be + i * 256, bg + i * 256, h);
  }

  final_k<<<M_DIM / 256, 256, 0, stream>>>(h, wTo, outb, x, (float*)d_out);
}